// Round 1
// baseline (202.568 us; speedup 1.0000x reference)
//
#include <hip/hip_runtime.h>

constexpr int B_ = 64;
constexpr int T_ = 2048;
constexpr int H_ = 256;
constexpr float NEGINF = -1e10f;  // matches reference -10**10

// ---------------------------------------------------------------------------
// prep1: partial[j][h] = sum_{k in [4j, 4j+4)} v[k] * W[k][h]
// W layout: W[k*H + h], h contiguous -> coalesced over threads (h = tid).
// Block 0 / thread 0 also computes c = v . b (tiny, pipelined scalar loop).
// ---------------------------------------------------------------------------
__global__ __launch_bounds__(256) void prep1_kernel(
    const float* __restrict__ W, const float* __restrict__ bias,
    const float* __restrict__ v, float* __restrict__ partial,
    float* __restrict__ cptr) {
  const int h = threadIdx.x;
  const int j = blockIdx.x;  // 0..63, each covers 4 k-values
  float acc = 0.f;
#pragma unroll
  for (int kk = 0; kk < 4; ++kk) {
    const int k = j * 4 + kk;
    acc += v[k] * W[k * H_ + h];
  }
  partial[j * H_ + h] = acc;
  if (j == 0 && h == 0) {
    float cc = 0.f;
#pragma unroll 8
    for (int k = 0; k < H_; ++k) cc += v[k] * bias[k];
    *cptr = cc;
  }
}

// ---------------------------------------------------------------------------
// prep2: u[h] = sum_j partial[j][h]   (64 KiB read, one block)
// ---------------------------------------------------------------------------
__global__ __launch_bounds__(256) void prep2_kernel(
    const float* __restrict__ partial, float* __restrict__ u) {
  const int h = threadIdx.x;
  float acc = 0.f;
#pragma unroll
  for (int j = 0; j < 64; ++j) acc += partial[j * H_ + h];
  u[h] = acc;
}

// ---------------------------------------------------------------------------
// energy: e[b,t] = q[b,t] . u + c  for t < len[b], else NEG_INF (q not read).
// One wave per token: lane i holds float4 of u (h = 4i..4i+3), loads the
// matching float4 of q (64 lanes x 16 B = 1024 B, fully coalesced), then a
// 6-step shfl_xor sum over 64 lanes.
// Grid: B * (T / TOK_PER_BLOCK) blocks, 256 threads (4 waves).
// ---------------------------------------------------------------------------
constexpr int TOK_PER_BLOCK = 128;

__global__ __launch_bounds__(256) void energy_kernel(
    const float* __restrict__ q, const int* __restrict__ lens,
    const float* __restrict__ u, const float* __restrict__ cptr,
    float* __restrict__ e) {
  const int chunks_per_row = T_ / TOK_PER_BLOCK;          // 16
  const int bb = blockIdx.x / chunks_per_row;
  const int t0 = (blockIdx.x % chunks_per_row) * TOK_PER_BLOCK;
  const int wave = threadIdx.x >> 6;
  const int lane = threadIdx.x & 63;
  const int len = lens[bb];
  const float c = *cptr;
  const float4 uv = reinterpret_cast<const float4*>(u)[lane];
  const float4* qrow =
      reinterpret_cast<const float4*>(q) + (size_t)bb * T_ * (H_ / 4);
  float* erow = e + (size_t)bb * T_;

  for (int i = wave; i < TOK_PER_BLOCK; i += 4) {
    const int t = t0 + i;
    if (t < len) {  // wave-uniform branch
      const float4 qv = qrow[(size_t)t * (H_ / 4) + lane];
      float s = qv.x * uv.x + qv.y * uv.y + qv.z * uv.z + qv.w * uv.w;
#pragma unroll
      for (int off = 32; off > 0; off >>= 1) s += __shfl_xor(s, off);
      if (lane == 0) erow[t] = s + c;
    } else {
      if (lane == 0) erow[t] = NEGINF;
    }
  }
}

// ---------------------------------------------------------------------------
// softmax: one block per batch row; 2048 values held in 8 regs/thread.
// Masked entries are -1e10 -> expf underflows to exactly 0, matching the
// reference's softmax over the -1e10-padded row.
// ---------------------------------------------------------------------------
__global__ __launch_bounds__(256) void softmax_kernel(
    const float* __restrict__ e, float* __restrict__ out) {
  const int bb = blockIdx.x;
  const int tid = threadIdx.x;
  const int wave = tid >> 6;
  const int lane = tid & 63;
  const float* erow = e + (size_t)bb * T_;
  float* orow = out + (size_t)bb * T_;

  float vals[T_ / 256];  // 8
  float m = NEGINF;
#pragma unroll
  for (int i = 0; i < T_ / 256; ++i) {
    vals[i] = erow[i * 256 + tid];
    m = fmaxf(m, vals[i]);
  }
#pragma unroll
  for (int off = 32; off > 0; off >>= 1) m = fmaxf(m, __shfl_xor(m, off));

  __shared__ float sm[4];
  __shared__ float ssum[4];
  if (lane == 0) sm[wave] = m;
  __syncthreads();
  m = fmaxf(fmaxf(sm[0], sm[1]), fmaxf(sm[2], sm[3]));

  float s = 0.f;
#pragma unroll
  for (int i = 0; i < T_ / 256; ++i) {
    vals[i] = expf(vals[i] - m);
    s += vals[i];
  }
#pragma unroll
  for (int off = 32; off > 0; off >>= 1) s += __shfl_xor(s, off);
  if (lane == 0) ssum[wave] = s;
  __syncthreads();
  s = ssum[0] + ssum[1] + ssum[2] + ssum[3];
  const float inv = 1.f / s;
#pragma unroll
  for (int i = 0; i < T_ / 256; ++i) orow[i * 256 + tid] = vals[i] * inv;
}

// ---------------------------------------------------------------------------
extern "C" void kernel_launch(void* const* d_in, const int* in_sizes, int n_in,
                              void* d_out, int out_size, void* d_ws,
                              size_t ws_size, hipStream_t stream) {
  const float* q = (const float*)d_in[0];     // [B,T,H]
  const int* lens = (const int*)d_in[1];      // [B]
  const float* W = (const float*)d_in[2];     // [H,H]
  const float* bias = (const float*)d_in[3];  // [H]
  const float* v = (const float*)d_in[4];     // [H]
  float* out = (float*)d_out;                 // [B,T]

  char* ws = (char*)d_ws;
  float* partial = (float*)ws;                       // 64*256 floats = 64 KiB
  float* u = (float*)(ws + 64 * H_ * sizeof(float)); // 256 floats
  float* c = (float*)(ws + 64 * H_ * sizeof(float) + H_ * sizeof(float));
  float* e = (float*)(ws + 131072);                  // B*T floats = 512 KiB

  prep1_kernel<<<dim3(64), dim3(256), 0, stream>>>(W, bias, v, partial, c);
  prep2_kernel<<<dim3(1), dim3(256), 0, stream>>>(partial, u);
  energy_kernel<<<dim3(B_ * (T_ / TOK_PER_BLOCK)), dim3(256), 0, stream>>>(
      q, lens, u, c, e);
  softmax_kernel<<<dim3(B_), dim3(256), 0, stream>>>(e, out);
}

// Round 2
// 192.279 us; speedup vs baseline: 1.0535x; 1.0535x over previous
//
#include <hip/hip_runtime.h>

constexpr int B_ = 64;
constexpr int T_ = 2048;
constexpr int H_ = 256;
constexpr float NEGINF = -1e10f;  // matches reference -10**10

// ---------------------------------------------------------------------------
// prep: 4 blocks; block j computes partial[j][h] = sum_{k in [64j,64j+64)}
// v[k] * W[k][h].  (u[h] = sum_j partial[j][h] is folded into energy_kernel.)
// The bias term v.b is dropped: it shifts all valid energies of a row
// uniformly, and softmax is shift-invariant (masked entries are exactly
// -1e10 in both formulations and underflow to 0 either way).
// ---------------------------------------------------------------------------
__global__ __launch_bounds__(256) void prep_kernel(
    const float* __restrict__ W, const float* __restrict__ v,
    float* __restrict__ partial) {
  const int h = threadIdx.x;
  const int j = blockIdx.x;  // 0..3
  float acc = 0.f;
#pragma unroll 8
  for (int kk = 0; kk < 64; ++kk) {
    const int k = j * 64 + kk;
    acc = fmaf(v[k], W[k * H_ + h], acc);
  }
  partial[j * H_ + h] = acc;
}

// ---------------------------------------------------------------------------
// energy: e[b,t] = q[b,t] . u  for t < len[b], else NEG_INF (q not read).
// Block = 256 threads <-> 256 tokens [t0, t0+256) of row bb.
//   thread: tg = tid>>3 (token group), c4 = tid&7 (float4 column chunk).
//   Preload uf[hh] = u[32*hh + 4*c4 .. +3] (8 reg float4s, summed from the
//   4 prep partials, L2-hot).
//   Loop i=0..7 over tokens t = t0+tg+32i: 8 float4 loads (128B contiguous
//   per 8-lane group) -> 32 FMA into acc[i]. Row-granular mask predication.
//   Reduce across the 8 column-chunk lanes: 3-step shfl_xor butterfly,
//   8 independent chains (full ILP). Lane c4 writes token tg+32*c4.
// Fully-masked blocks write NEGINF with zero q traffic.
// ---------------------------------------------------------------------------
__global__ __launch_bounds__(256) void energy_kernel(
    const float4* __restrict__ q4, const int* __restrict__ lens,
    const float4* __restrict__ p4,  // [4][64] float4 partials of u
    float* __restrict__ e) {
  const int bb = blockIdx.y;
  const int t0 = blockIdx.x * 256;
  const int len = lens[bb];
  const int tid = threadIdx.x;
  float* erow = e + (size_t)bb * T_;

  if (t0 >= len) {  // whole block masked: no q reads at all
    erow[t0 + tid] = NEGINF;
    return;
  }

  const int tg = tid >> 3;  // 0..31
  const int c4 = tid & 7;   // 0..7

  // uf[hh] = sum of 4 partials, chunk (hh*8 + c4)
  float4 uf[8];
#pragma unroll
  for (int hh = 0; hh < 8; ++hh) {
    float4 s = p4[hh * 8 + c4];
#pragma unroll
    for (int j = 1; j < 4; ++j) {
      const float4 t = p4[j * 64 + hh * 8 + c4];
      s.x += t.x; s.y += t.y; s.z += t.z; s.w += t.w;
    }
    uf[hh] = s;
  }

  const float4* qbase =
      q4 + ((size_t)bb * T_ + t0 + tg) * (H_ / 4) + c4;

  float acc[8];
#pragma unroll
  for (int i = 0; i < 8; ++i) acc[i] = 0.f;

#pragma unroll
  for (int i = 0; i < 8; ++i) {
    const int t = t0 + tg + 32 * i;
    if (t < len) {  // divergent only in the single boundary block
      const float4* qp = qbase + (size_t)i * 32 * (H_ / 4);
#pragma unroll
      for (int hh = 0; hh < 8; ++hh) {
        const float4 qv = qp[hh * 8];  // imm-offset loads, one base per i
        acc[i] = fmaf(qv.x, uf[hh].x, acc[i]);
        acc[i] = fmaf(qv.y, uf[hh].y, acc[i]);
        acc[i] = fmaf(qv.z, uf[hh].z, acc[i]);
        acc[i] = fmaf(qv.w, uf[hh].w, acc[i]);
      }
    }
  }

  // sum over the 8 column-chunk lanes (lanes sharing tg)
#pragma unroll
  for (int off = 1; off < 8; off <<= 1) {
#pragma unroll
    for (int i = 0; i < 8; ++i) acc[i] += __shfl_xor(acc[i], off);
  }

  // lane c4 writes token tg + 32*c4 (static-index select, no scratch)
  float val = 0.f;
#pragma unroll
  for (int k = 0; k < 8; ++k)
    if (c4 == k) val = acc[k];
  const int t = t0 + tg + 32 * c4;
  erow[t] = (t < len) ? val : NEGINF;
}

// ---------------------------------------------------------------------------
// softmax: one block per batch row; 2048 values in 8 regs/thread.
// Masked entries (-1e10) underflow to exactly 0 after exp, matching the
// reference's softmax over the -1e10-padded row.
// ---------------------------------------------------------------------------
__global__ __launch_bounds__(256) void softmax_kernel(
    const float* __restrict__ e, float* __restrict__ out) {
  const int bb = blockIdx.x;
  const int tid = threadIdx.x;
  const int wave = tid >> 6;
  const int lane = tid & 63;
  const float* erow = e + (size_t)bb * T_;
  float* orow = out + (size_t)bb * T_;

  float vals[T_ / 256];  // 8
  float m = NEGINF;
#pragma unroll
  for (int i = 0; i < T_ / 256; ++i) {
    vals[i] = erow[i * 256 + tid];
    m = fmaxf(m, vals[i]);
  }
#pragma unroll
  for (int off = 32; off > 0; off >>= 1) m = fmaxf(m, __shfl_xor(m, off));

  __shared__ float sm[4];
  __shared__ float ssum[4];
  if (lane == 0) sm[wave] = m;
  __syncthreads();
  m = fmaxf(fmaxf(sm[0], sm[1]), fmaxf(sm[2], sm[3]));

  float s = 0.f;
#pragma unroll
  for (int i = 0; i < T_ / 256; ++i) {
    vals[i] = expf(vals[i] - m);
    s += vals[i];
  }
#pragma unroll
  for (int off = 32; off > 0; off >>= 1) s += __shfl_xor(s, off);
  if (lane == 0) ssum[wave] = s;
  __syncthreads();
  s = ssum[0] + ssum[1] + ssum[2] + ssum[3];
  const float inv = 1.f / s;
#pragma unroll
  for (int i = 0; i < T_ / 256; ++i) orow[i * 256 + tid] = vals[i] * inv;
}

// ---------------------------------------------------------------------------
extern "C" void kernel_launch(void* const* d_in, const int* in_sizes, int n_in,
                              void* d_out, int out_size, void* d_ws,
                              size_t ws_size, hipStream_t stream) {
  const float* q = (const float*)d_in[0];     // [B,T,H]
  const int* lens = (const int*)d_in[1];      // [B]
  const float* W = (const float*)d_in[2];     // [H,H]
  // d_in[3] = bias, d_in[4] = v; bias unused (softmax shift-invariance)
  const float* v = (const float*)d_in[4];
  float* out = (float*)d_out;                 // [B,T]

  char* ws = (char*)d_ws;
  float* partial = (float*)ws;                  // 4*256 floats = 4 KiB
  float* e = (float*)(ws + 8192);               // B*T floats = 512 KiB

  prep_kernel<<<dim3(4), dim3(256), 0, stream>>>(W, v, partial);
  energy_kernel<<<dim3(T_ / 256, B_), dim3(256), 0, stream>>>(
      (const float4*)q, lens, (const float4*)partial, e);
  softmax_kernel<<<dim3(B_), dim3(256), 0, stream>>>(e, out);
}